// Round 2
// baseline (629.421 us; speedup 1.0000x reference)
//
#include <hip/hip_runtime.h>

// RGCN 2-layer, N=100000, E=3200000, R=8, H=C=16.
// Gather formulation: sort edges by dst (histogram+scan+permute), then per
// node accumulate 8 per-relation x-sums (no atomics, no per-edge matmul);
// transform = block of 4 MFMAs (S[16x128] @ Wcat[128x16]) + root MFMA,
// fused relu / log_softmax epilogue. h stored bf16 for layer-2 gathers.

constexpr int NN = 100000;
constexpr int NE = 3200000;

typedef short bf16x8 __attribute__((ext_vector_type(8)));
typedef float f32x4 __attribute__((ext_vector_type(4)));

__device__ __forceinline__ short f2bf(float f) {
  union { float f; unsigned u; } v; v.f = f;
  unsigned r = v.u + 0x7FFFu + ((v.u >> 16) & 1u);  // RNE
  return (short)(r >> 16);
}
__device__ __forceinline__ float bf2f(unsigned short u) {
  union { unsigned u; float f; } v; v.u = ((unsigned)u) << 16; return v.f;
}

// K1: per-(dst, relation) histogram.
__global__ void __launch_bounds__(256) count_kernel(
    const int* __restrict__ dst, const int* __restrict__ typ,
    unsigned* __restrict__ cnt) {
  int e = blockIdx.x * 256 + threadIdx.x;
  atomicAdd(&cnt[(unsigned)dst[e] * 8u + (unsigned)typ[e]], 1u);
}

// K2a: per-block exclusive scan of deg[i] = sum_r cnt[i][r].
__global__ void __launch_bounds__(256) scanA_kernel(
    const unsigned* __restrict__ cnt, unsigned* __restrict__ off,
    unsigned* __restrict__ bsum) {
  __shared__ unsigned sh[256];
  int i = blockIdx.x * 256 + threadIdx.x;
  unsigned deg = 0;
  if (i < NN) {
    const uint4* cp = reinterpret_cast<const uint4*>(cnt + (size_t)i * 8);
    uint4 a = cp[0], b = cp[1];
    deg = a.x + a.y + a.z + a.w + b.x + b.y + b.z + b.w;
  }
  sh[threadIdx.x] = deg;
  __syncthreads();
  for (int d = 1; d < 256; d <<= 1) {
    unsigned t = (threadIdx.x >= d) ? sh[threadIdx.x - d] : 0u;
    __syncthreads();
    sh[threadIdx.x] += t;
    __syncthreads();
  }
  if (i < NN) off[i] = sh[threadIdx.x] - deg;  // block-local exclusive
  if (threadIdx.x == 255) bsum[blockIdx.x] = sh[255];
}

// K2b: exclusive scan of the 391 block sums (single block).
__global__ void __launch_bounds__(512) scanB_kernel(unsigned* __restrict__ bsum,
                                                    const int nb) {
  __shared__ unsigned sh[512];
  int t = threadIdx.x;
  unsigned v = (t < nb) ? bsum[t] : 0u;
  sh[t] = v;
  __syncthreads();
  for (int d = 1; d < 512; d <<= 1) {
    unsigned u = (t >= d) ? sh[t - d] : 0u;
    __syncthreads();
    sh[t] += u;
    __syncthreads();
  }
  if (t < nb) bsum[t] = sh[t] - v;
}

// K2c: finalize off, init cursor, compute invc in place over cnt.
__global__ void __launch_bounds__(256) scanC_kernel(
    unsigned* __restrict__ cnt_invc, unsigned* __restrict__ off,
    unsigned* __restrict__ cursor, const unsigned* __restrict__ bsum) {
  int i = blockIdx.x * 256 + threadIdx.x;
  if (i >= NN) return;
  unsigned fin = off[i] + bsum[blockIdx.x];
  off[i] = fin;
  cursor[i] = fin;
  uint4* cp = reinterpret_cast<uint4*>(cnt_invc + (size_t)i * 8);
  uint4 a = cp[0], b = cp[1];
  if (i == NN - 1)
    off[NN] = fin + a.x + a.y + a.z + a.w + b.x + b.y + b.z + b.w;
  float4 ia, ib;
  ia.x = 1.f / (float)(a.x ? a.x : 1u); ia.y = 1.f / (float)(a.y ? a.y : 1u);
  ia.z = 1.f / (float)(a.z ? a.z : 1u); ia.w = 1.f / (float)(a.w ? a.w : 1u);
  ib.x = 1.f / (float)(b.x ? b.x : 1u); ib.y = 1.f / (float)(b.y ? b.y : 1u);
  ib.z = 1.f / (float)(b.z ? b.z : 1u); ib.w = 1.f / (float)(b.w ? b.w : 1u);
  float4* ip = reinterpret_cast<float4*>(cnt_invc + (size_t)i * 8);
  ip[0] = ia; ip[1] = ib;
}

// K3: bucket edges by dst: packed[pos] = src | (rel<<17).
__global__ void __launch_bounds__(256) permute_kernel(
    const int* __restrict__ src, const int* __restrict__ dst,
    const int* __restrict__ typ, unsigned* __restrict__ cursor,
    unsigned* __restrict__ packed) {
  int e = blockIdx.x * 256 + threadIdx.x;
  int d = dst[e];
  unsigned pos = atomicAdd(&cursor[d], 1u);
  packed[pos] = (unsigned)src[e] | ((unsigned)typ[e] << 17);
}

// K4/K5: fused layer. Wave = 16 nodes; lanes (g=lane>>4, c=lane&15).
// Group g walks nodes 4g..4g+3 (16 lanes = feature components), building
// per-relation sums in regs; flush scaled sums to LDS S[node][rel][comp];
// then 4 MFMAs (rel blocks) + root MFMA + epilogue.
template <int MODE>
__global__ void __launch_bounds__(256) layer_kernel(
    const float* __restrict__ Xf, const unsigned short* __restrict__ Xh,
    const float* __restrict__ W, const float* __restrict__ ROOT,
    const float* __restrict__ BIAS, const float* __restrict__ invc,
    const unsigned* __restrict__ off, const unsigned* __restrict__ packed,
    unsigned short* __restrict__ Hout, float* __restrict__ Fout) {
  __shared__ float S[4][16 * 132];  // node stride 132: 2-way-max LDS banks
  const int tid = threadIdx.x;
  const int wv = tid >> 6;
  const int lane = tid & 63;
  const int c = lane & 15;
  const int g = lane >> 4;
  const int n0 = (blockIdx.x * 4 + wv) * 16;
  const bool valid = (n0 < NN);
  float* Sw = S[wv];

  auto LDX = [&](unsigned pk) -> float {
    unsigned sr = pk & 0x1FFFFu;
    if (MODE) return bf2f(Xh[(size_t)sr * 16 + c]);
    return Xf[(size_t)sr * 16 + c];
  };

  if (valid) {
    for (int k = 0; k < 4; ++k) {
      const int ndl = 4 * g + k;
      const int nd = n0 + ndl;
      unsigned p = off[nd], pe = off[nd + 1];
      float s0 = 0.f, s1 = 0.f, s2 = 0.f, s3 = 0.f,
            s4 = 0.f, s5 = 0.f, s6 = 0.f, s7 = 0.f;
      auto ACC = [&](unsigned pk, float xv) {
        unsigned rr = pk >> 17;
        s0 += (rr == 0u) ? xv : 0.f; s1 += (rr == 1u) ? xv : 0.f;
        s2 += (rr == 2u) ? xv : 0.f; s3 += (rr == 3u) ? xv : 0.f;
        s4 += (rr == 4u) ? xv : 0.f; s5 += (rr == 5u) ? xv : 0.f;
        s6 += (rr == 6u) ? xv : 0.f; s7 += (rr == 7u) ? xv : 0.f;
      };
      for (; p + 4 <= pe; p += 4) {  // 4 gathers in flight
        unsigned pk0 = packed[p], pk1 = packed[p + 1];
        unsigned pk2 = packed[p + 2], pk3 = packed[p + 3];
        float x0 = LDX(pk0), x1 = LDX(pk1), x2 = LDX(pk2), x3 = LDX(pk3);
        ACC(pk0, x0); ACC(pk1, x1); ACC(pk2, x2); ACC(pk3, x3);
      }
      for (; p < pe; ++p) {
        unsigned pk = packed[p];
        ACC(pk, LDX(pk));
      }
      const float4* ivp = reinterpret_cast<const float4*>(invc + (size_t)nd * 8);
      float4 iva = ivp[0], ivb = ivp[1];
      float* sp = Sw + ndl * 132;
      sp[0 * 16 + c] = s0 * iva.x; sp[1 * 16 + c] = s1 * iva.y;
      sp[2 * 16 + c] = s2 * iva.z; sp[3 * 16 + c] = s3 * iva.w;
      sp[4 * 16 + c] = s4 * ivb.x; sp[5 * 16 + c] = s5 * ivb.y;
      sp[6 * 16 + c] = s6 * ivb.z; sp[7 * 16 + c] = s7 * ivb.w;
    }
  }
  __syncthreads();
  if (!valid) return;

  // B fragments: Wcat rel blocks + root. lane: col=c, k = g*8+j.
  bf16x8 b0, b1, b2, b3, brt;
#pragma unroll
  for (int j = 0; j < 8; ++j) {
    int kq = g * 8 + j; int rb = kq >> 4; int kk = kq & 15;
    b0[j] = f2bf(W[(rb + 0) * 256 + kk * 16 + c]);
    b1[j] = f2bf(W[(rb + 2) * 256 + kk * 16 + c]);
    b2[j] = f2bf(W[(rb + 4) * 256 + kk * 16 + c]);
    b3[j] = f2bf(W[(rb + 6) * 256 + kk * 16 + c]);
    brt[j] = (kq < 16) ? f2bf(ROOT[kq * 16 + c]) : (short)0;
  }

  // A fragments: row=node=c(lane&15), rel = 2m + (g>>1), comps (g&1)*8..+7.
  const int kk0 = (g & 1) * 8;
  const int rsel = g >> 1;
  bf16x8 a0, a1, a2, a3;
#define LDA(AM, M)                                                        \
  {                                                                       \
    const float* sp2 = Sw + c * 132 + (2 * (M) + rsel) * 16 + kk0;        \
    float4 u = *reinterpret_cast<const float4*>(sp2);                     \
    float4 v2 = *reinterpret_cast<const float4*>(sp2 + 4);                \
    AM[0] = f2bf(u.x); AM[1] = f2bf(u.y); AM[2] = f2bf(u.z);              \
    AM[3] = f2bf(u.w); AM[4] = f2bf(v2.x); AM[5] = f2bf(v2.y);            \
    AM[6] = f2bf(v2.z); AM[7] = f2bf(v2.w);                               \
  }
  LDA(a0, 0) LDA(a1, 1) LDA(a2, 2) LDA(a3, 3)
#undef LDA

  bf16x8 ar = {0, 0, 0, 0, 0, 0, 0, 0};
  if (g < 2) {
    if (MODE == 0) {
      const float* xp = Xf + (size_t)(n0 + c) * 16 + g * 8;
      float4 pp = *reinterpret_cast<const float4*>(xp);
      float4 qq = *reinterpret_cast<const float4*>(xp + 4);
      ar[0] = f2bf(pp.x); ar[1] = f2bf(pp.y); ar[2] = f2bf(pp.z);
      ar[3] = f2bf(pp.w); ar[4] = f2bf(qq.x); ar[5] = f2bf(qq.y);
      ar[6] = f2bf(qq.z); ar[7] = f2bf(qq.w);
    } else {
      ar = *reinterpret_cast<const bf16x8*>(Xh + (size_t)(n0 + c) * 16 + g * 8);
    }
  }

  const float bc = BIAS[c];
  f32x4 acc = {bc, bc, bc, bc};
  acc = __builtin_amdgcn_mfma_f32_16x16x32_bf16(a0, b0, acc, 0, 0, 0);
  acc = __builtin_amdgcn_mfma_f32_16x16x32_bf16(a1, b1, acc, 0, 0, 0);
  acc = __builtin_amdgcn_mfma_f32_16x16x32_bf16(a2, b2, acc, 0, 0, 0);
  acc = __builtin_amdgcn_mfma_f32_16x16x32_bf16(a3, b3, acc, 0, 0, 0);
  acc = __builtin_amdgcn_mfma_f32_16x16x32_bf16(ar, brt, acc, 0, 0, 0);

  // D layout: col=lane&15 (=feature c), row=g*4+r2 (=node).
  if (MODE == 0) {
#pragma unroll
    for (int r2 = 0; r2 < 4; ++r2) {
      int node = n0 + g * 4 + r2;
      Hout[(size_t)node * 16 + c] = (unsigned short)f2bf(fmaxf(acc[r2], 0.f));
    }
  } else {
#pragma unroll
    for (int r2 = 0; r2 < 4; ++r2) {
      int node = n0 + g * 4 + r2;
      float zv = acc[r2];
      float mx = zv;
      mx = fmaxf(mx, __shfl_xor(mx, 1));
      mx = fmaxf(mx, __shfl_xor(mx, 2));
      mx = fmaxf(mx, __shfl_xor(mx, 4));
      mx = fmaxf(mx, __shfl_xor(mx, 8));
      float sm = expf(zv - mx);
      sm += __shfl_xor(sm, 1);
      sm += __shfl_xor(sm, 2);
      sm += __shfl_xor(sm, 4);
      sm += __shfl_xor(sm, 8);
      Fout[(size_t)node * 16 + c] = zv - mx - logf(sm);
    }
  }
}

extern "C" void kernel_launch(void* const* d_in, const int* in_sizes, int n_in,
                              void* d_out, int out_size, void* d_ws, size_t ws_size,
                              hipStream_t stream) {
  const float* embed = (const float*)d_in[0];
  const float* W1    = (const float*)d_in[1];
  const float* root1 = (const float*)d_in[2];
  const float* b1    = (const float*)d_in[3];
  const float* W2    = (const float*)d_in[4];
  const float* root2 = (const float*)d_in[5];
  const float* b2    = (const float*)d_in[6];
  const int* eidx    = (const int*)d_in[7];
  const int* etyp    = (const int*)d_in[8];
  const int* src = eidx;
  const int* dst = eidx + NE;
  float* out = (float*)d_out;

  // ws layout (u32 units): cnt/invc[800000] | off[100001(+3)] | cursor[100000]
  //                        | bsum[512] | packed[3200000] | h (bf16, 1.6M ushort)
  unsigned* cnt    = (unsigned*)d_ws;           // aliases invc (f32, in place)
  float*    invc   = (float*)d_ws;
  unsigned* off    = cnt + 800000;              // 100001 entries
  unsigned* cursor = off + 100004;
  unsigned* bsum   = cursor + 100000;
  unsigned* packed = bsum + 512;
  unsigned short* h = (unsigned short*)(packed + NE);  // 16B-aligned

  hipMemsetAsync(cnt, 0, 800000 * 4, stream);
  count_kernel<<<NE / 256, 256, 0, stream>>>(dst, etyp, cnt);
  scanA_kernel<<<391, 256, 0, stream>>>(cnt, off, bsum);
  scanB_kernel<<<1, 512, 0, stream>>>(bsum, 391);
  scanC_kernel<<<391, 256, 0, stream>>>(cnt, off, cursor, bsum);
  permute_kernel<<<NE / 256, 256, 0, stream>>>(src, dst, etyp, cursor, packed);

  layer_kernel<0><<<1563, 256, 0, stream>>>(embed, h, W1, root1, b1, invc,
                                            off, packed, h, out);
  layer_kernel<1><<<1563, 256, 0, stream>>>(embed, h, W2, root2, b2, invc,
                                            off, packed, h, out);
}